// Round 10
// baseline (178.829 us; speedup 1.0000x reference)
//
#include <hip/hip_runtime.h>
#include <math.h>

// Performer FAVOR+ feature map — wave-autonomous, barrier-free, LDS-free,
// non-temporal memory politeness (R10 = R9 with ext_vector_type for nt ops).
//   out[t][j] = exp2( x[t].(nrm*log2e*proj[j]) + dlog[t] ) + ratio*eps
//   dlog[t] = -0.5*||x[t]||^2*log2e - 4   (ratio=2^-4 folded into exponent)
//   bf16 hi/lo 3-term MFMA (drop lo*lo; absmax 3e-8, verified R2..R8).
//
// nt rationale: out (134 MB) stops allocating/dirtying L2 (was cycling the
// 4 MiB/XCD L2 4x with dirty evictions contending with reads); x (33.5 MB,
// zero reuse) stops polluting L2; bfrag (64 KB) stays hot.

typedef short bf16x8 __attribute__((ext_vector_type(8)));
typedef float f32x4  __attribute__((ext_vector_type(4)));

__device__ __forceinline__ unsigned short f2bf_rne(float f) {
    unsigned u = __builtin_bit_cast(unsigned, f);
    unsigned r = u + 0x7FFFu + ((u >> 16) & 1u);
    return (unsigned short)(r >> 16);
}

__device__ __forceinline__ void f2bf_hilo(float f, unsigned short& h, unsigned short& l) {
    h = f2bf_rne(f);
    float fh = __builtin_bit_cast(float, (unsigned)h << 16);
    l = f2bf_rne(f - fh);
}

// ---- prep_b: proj (256x64 fp32) -> frag-ordered bf16 hi/lo (64 KB) ----
// index ((nf*2 + kc)*2 + h)*64 + lane, 8 bf16 each. Scale = 64^-0.25 * log2(e).
__global__ void performer_prep_b(const float* __restrict__ proj, short* __restrict__ bfrag) {
    int g    = blockIdx.x * 256 + threadIdx.x;   // 0..4095
    int lane = g & 63;
    int h    = (g >> 6) & 1;
    int kc   = (g >> 7) & 1;
    int nf   = g >> 8;                           // 0..15
    int n    = nf * 16 + (lane & 15);
    int kb   = kc * 32 + (lane >> 4) * 8;
    const float scl = 0.51006972784f;            // 64^-0.25 * log2(e)
    float4 v0 = *(const float4*)&proj[n * 64 + kb];
    float4 v1 = *(const float4*)&proj[n * 64 + kb + 4];
    float vals[8] = {v0.x, v0.y, v0.z, v0.w, v1.x, v1.y, v1.z, v1.w};
    union { unsigned short us[8]; bf16x8 v; } o;
    #pragma unroll
    for (int j = 0; j < 8; ++j) {
        unsigned short hi, lo;
        f2bf_hilo(vals[j] * scl, hi, lo);
        o.us[j] = h ? lo : hi;
    }
    *(bf16x8*)&bfrag[g * 8] = o.v;
}

// convert one token-set (4 x 16B of x) into 4 MFMA frags + dl
__device__ __forceinline__ void build_xfrags(const f32x4* xr, int q,
                                             bf16x8& xh0, bf16x8& xl0,
                                             bf16x8& xh1, bf16x8& xl1,
                                             float& dl) {
    f32x4 a0 = __builtin_nontemporal_load(xr + q * 2);      // k = q*8..q*8+3
    f32x4 a1 = __builtin_nontemporal_load(xr + q * 2 + 1);  // k = q*8+4..+7
    f32x4 a2 = __builtin_nontemporal_load(xr + 8 + q * 2);  // k = 32+q*8..
    f32x4 a3 = __builtin_nontemporal_load(xr + 8 + q * 2 + 1);

    float p = a0.x * a0.x + a0.y * a0.y + a0.z * a0.z + a0.w * a0.w
            + a1.x * a1.x + a1.y * a1.y + a1.z * a1.z + a1.w * a1.w
            + a2.x * a2.x + a2.y * a2.y + a2.z * a2.z + a2.w * a2.w
            + a3.x * a3.x + a3.y * a3.y + a3.z * a3.z + a3.w * a3.w;
    p += __shfl_xor(p, 16);
    p += __shfl_xor(p, 32);         // all 4 q-lanes of token li now hold ||x||^2
    const float NHL2E = -0.7213475204444817f;    // -0.5*log2(e)
    dl = fmaf(NHL2E, p, -4.0f);

    float v0[8] = {a0.x, a0.y, a0.z, a0.w, a1.x, a1.y, a1.z, a1.w};
    float v1[8] = {a2.x, a2.y, a2.z, a2.w, a3.x, a3.y, a3.z, a3.w};
    union { unsigned short us[8]; bf16x8 v; } h0, l0, h1, l1;
    #pragma unroll
    for (int j = 0; j < 8; ++j) {
        f2bf_hilo(v0[j], h0.us[j], l0.us[j]);
        f2bf_hilo(v1[j], h1.us[j], l1.us[j]);
    }
    xh0 = h0.v; xl0 = l0.v; xh1 = h1.v; xl1 = l1.v;
}

// ---- main: 256 thr = 4 waves; wave owns 32 tokens x 256 feats ----
__global__ __launch_bounds__(256, 5)
void performer_fm_kernel(const float* __restrict__ x,
                         const short* __restrict__ bfrag,
                         float* __restrict__ out) {
    const int wave = threadIdx.x >> 6;
    const int lane = threadIdx.x & 63;
    const int q    = lane >> 4;
    const int li   = lane & 15;
    const long t0  = ((long)blockIdx.x * 4 + wave) * 32;

    // x-frags for token sets A (t0+li) and B (t0+16+li), built once
    bf16x8 ah0, al0, ah1, al1, bh0, bl0, bh1, bl1;
    float dla, dlb;
    build_xfrags((const f32x4*)(x + (t0 + li) * 64),      q, ah0, al0, ah1, al1, dla);
    build_xfrags((const f32x4*)(x + (t0 + 16 + li) * 64), q, bh0, bl0, bh1, bl1, dlb);

    const bf16x8* bw = (const bf16x8*)bfrag;
    const float REPS = 6.25e-6f;                 // ratio*eps

    float* orowA = out + (t0 + li) * 256 + q * 4;
    float* orowB = orowA + 16 * 256;

    #pragma unroll 2
    for (int nf = 0; nf < 16; ++nf) {
        // proj frags for feature tile nf (L2-hot, independent of acc chain)
        bf16x8 Ph0 = bw[(nf * 4 + 0) * 64 + lane];   // kc0 hi
        bf16x8 Pl0 = bw[(nf * 4 + 1) * 64 + lane];   // kc0 lo
        bf16x8 Ph1 = bw[(nf * 4 + 2) * 64 + lane];   // kc1 hi
        bf16x8 Pl1 = bw[(nf * 4 + 3) * 64 + lane];   // kc1 lo

        f32x4 accA = {0.f, 0.f, 0.f, 0.f};
        f32x4 accB = {0.f, 0.f, 0.f, 0.f};
        accA = __builtin_amdgcn_mfma_f32_16x16x32_bf16(Pl0, ah0, accA, 0, 0, 0);
        accB = __builtin_amdgcn_mfma_f32_16x16x32_bf16(Pl0, bh0, accB, 0, 0, 0);
        accA = __builtin_amdgcn_mfma_f32_16x16x32_bf16(Ph0, al0, accA, 0, 0, 0);
        accB = __builtin_amdgcn_mfma_f32_16x16x32_bf16(Ph0, bl0, accB, 0, 0, 0);
        accA = __builtin_amdgcn_mfma_f32_16x16x32_bf16(Ph0, ah0, accA, 0, 0, 0);
        accB = __builtin_amdgcn_mfma_f32_16x16x32_bf16(Ph0, bh0, accB, 0, 0, 0);
        accA = __builtin_amdgcn_mfma_f32_16x16x32_bf16(Pl1, ah1, accA, 0, 0, 0);
        accB = __builtin_amdgcn_mfma_f32_16x16x32_bf16(Pl1, bh1, accB, 0, 0, 0);
        accA = __builtin_amdgcn_mfma_f32_16x16x32_bf16(Ph1, al1, accA, 0, 0, 0);
        accB = __builtin_amdgcn_mfma_f32_16x16x32_bf16(Ph1, bl1, accB, 0, 0, 0);
        accA = __builtin_amdgcn_mfma_f32_16x16x32_bf16(Ph1, ah1, accA, 0, 0, 0);
        accB = __builtin_amdgcn_mfma_f32_16x16x32_bf16(Ph1, bh1, accB, 0, 0, 0);

        // D: col = li (token), row = q*4 + r (feature) -> nt 16B store
        f32x4 oA, oB;
        oA.x = __builtin_amdgcn_exp2f(accA.x + dla) + REPS;
        oA.y = __builtin_amdgcn_exp2f(accA.y + dla) + REPS;
        oA.z = __builtin_amdgcn_exp2f(accA.z + dla) + REPS;
        oA.w = __builtin_amdgcn_exp2f(accA.w + dla) + REPS;
        oB.x = __builtin_amdgcn_exp2f(accB.x + dlb) + REPS;
        oB.y = __builtin_amdgcn_exp2f(accB.y + dlb) + REPS;
        oB.z = __builtin_amdgcn_exp2f(accB.z + dlb) + REPS;
        oB.w = __builtin_amdgcn_exp2f(accB.w + dlb) + REPS;
        __builtin_nontemporal_store(oA, (f32x4*)(orowA + nf * 16));
        __builtin_nontemporal_store(oB, (f32x4*)(orowB + nf * 16));
    }
}

extern "C" void kernel_launch(void* const* d_in, const int* in_sizes, int n_in,
                              void* d_out, int out_size, void* d_ws, size_t ws_size,
                              hipStream_t stream) {
    const float* x    = (const float*)d_in[0];
    const float* proj = (const float*)d_in[1];
    float* out        = (float*)d_out;
    short* bfrag      = (short*)d_ws;            // 64 KB frag-ordered proj
    const int ntok    = in_sizes[0] / 64;        // 131072

    performer_prep_b<<<16, 256, 0, stream>>>(proj, bfrag);
    performer_fm_kernel<<<ntok / 128, 256, 0, stream>>>(x, bfrag, out);
}

// Round 11
// 158.139 us; speedup vs baseline: 1.1308x; 1.1308x over previous
//
#include <hip/hip_runtime.h>
#include <math.h>

// Performer FAVOR+ feature map — SINGLE kernel (R11 = R6 minus prep_b).
//   out[t][j] = ratio*(exp( x[t].(nrm*proj[j]) - 0.5*||x[t]||^2 ) + eps)
//             = exp2( acc*log2e + dlog[t] ) + ratio*eps
//   dlog[t] = -0.5*||x[t]||^2*log2e - 4   (ratio=2^-4 folded into exponent)
//   bf16 hi/lo 3-term MFMA (drop lo*lo; absmax 3e-8, verified R2..R10).
//
// R11 delta vs R6 (best, 161.5): prep_b kernel removed; each wave builds its
// 8 proj frags in-register from plain float4 loads of proj (64 KB, L2-hot):
// frag element j of (nf,kc) for lane (q,li) is proj[nf16+li][kc*32+q*8+j].
// Saves one launch + inter-kernel gap (R5->R6 measured ~8.8us for same).
//
// Main: 512 thr = 8 waves, tile 128 tokens x 256 feats.
//   Stage: wave w cvts its 16 tokens -> hi/lo bf16 x-frags in LDS (32 KB,
//   conflict-free ds_write_b128), dlog via 2 shfl. One barrier.
//   Compute: wave w owns feats [32w,32w+32): 8 token tiles x
//   { 4 ds_read_b128 + 12 MFMA + 8 exp2 + scalar stores }.

typedef short bf16x8 __attribute__((ext_vector_type(8)));
typedef float f32x4  __attribute__((ext_vector_type(4)));

__device__ __forceinline__ unsigned short f2bf_rne(float f) {
    unsigned u = __builtin_bit_cast(unsigned, f);
    unsigned r = u + 0x7FFFu + ((u >> 16) & 1u);
    return (unsigned short)(r >> 16);
}

__device__ __forceinline__ void f2bf_hilo(float f, unsigned short& h, unsigned short& l) {
    h = f2bf_rne(f);
    float fh = __builtin_bit_cast(float, (unsigned)h << 16);
    l = f2bf_rne(f - fh);
}

__global__ __launch_bounds__(512, 4)
void performer_fm_kernel(const float* __restrict__ x,
                         const float* __restrict__ proj,
                         float* __restrict__ out) {
    // x frags: 8 tt x 4 frags(h0,l0,h1,l1) x 64 lanes x 16 B = 32 KB
    __shared__ __align__(16) short Af[8 * 4 * 64 * 8];
    __shared__ float dlg[128];

    const int wave = threadIdx.x >> 6;
    const int lane = threadIdx.x & 63;
    const int q    = lane >> 4;
    const int li   = lane & 15;
    const long t0  = (long)blockIdx.x * 128;

    // ---- staging: wave w -> tokens [t0+16w, t0+16w+16) ----
    const float4* xr = (const float4*)(x + (t0 + wave * 16 + li) * 64);
    float4 a0 = xr[q * 2];          // k = q*8 .. q*8+3
    float4 a1 = xr[q * 2 + 1];      // k = q*8+4 .. q*8+7
    float4 a2 = xr[8 + q * 2];      // k = 32+q*8 ..
    float4 a3 = xr[8 + q * 2 + 1];

    // ---- proj fragments built in-register (L2-hot, overlaps x latency) ----
    // frag elem j of (nf,kc): proj[(wave*2+nf)*16+li][kc*32+q*8+j] * nrm
    bf16x8 Ph[2][2], Pl[2][2];
    {
        const float nrm = 0.35355339059327373f;  // 64^-0.25
        #pragma unroll
        for (int nf = 0; nf < 2; ++nf) {
            const int n = (wave * 2 + nf) * 16 + li;
            #pragma unroll
            for (int kc = 0; kc < 2; ++kc) {
                const int kb = kc * 32 + q * 8;
                float4 v0 = *(const float4*)&proj[n * 64 + kb];
                float4 v1 = *(const float4*)&proj[n * 64 + kb + 4];
                float vals[8] = {v0.x, v0.y, v0.z, v0.w, v1.x, v1.y, v1.z, v1.w};
                union { unsigned short us[8]; bf16x8 v; } hh, ll;
                #pragma unroll
                for (int j = 0; j < 8; ++j)
                    f2bf_hilo(vals[j] * nrm, hh.us[j], ll.us[j]);
                Ph[nf][kc] = hh.v;
                Pl[nf][kc] = ll.v;
            }
        }
    }

    // exact fp32 ||x||^2 for token (16w+li): reduce across q groups
    float p = a0.x * a0.x + a0.y * a0.y + a0.z * a0.z + a0.w * a0.w
            + a1.x * a1.x + a1.y * a1.y + a1.z * a1.z + a1.w * a1.w
            + a2.x * a2.x + a2.y * a2.y + a2.z * a2.z + a2.w * a2.w
            + a3.x * a3.x + a3.y * a3.y + a3.z * a3.z + a3.w * a3.w;
    p += __shfl_xor(p, 16);
    p += __shfl_xor(p, 32);
    const float NHL2E = -0.7213475204444817f;    // -0.5*log2(e)
    if (q == 0) dlg[wave * 16 + li] = fmaf(NHL2E, p, -4.0f);

    // register hi/lo pack -> LDS frags (conflict-free b128 at base+lane*16)
    {
        float v0[8] = {a0.x, a0.y, a0.z, a0.w, a1.x, a1.y, a1.z, a1.w};
        float v1[8] = {a2.x, a2.y, a2.z, a2.w, a3.x, a3.y, a3.z, a3.w};
        union { unsigned short us[8]; bf16x8 v; } h0, l0, h1, l1;
        #pragma unroll
        for (int j = 0; j < 8; ++j) {
            f2bf_hilo(v0[j], h0.us[j], l0.us[j]);
            f2bf_hilo(v1[j], h1.us[j], l1.us[j]);
        }
        bf16x8* As = (bf16x8*)Af;
        const int base = wave * 4 * 64 + lane;   // tt = wave
        As[base]       = h0.v;
        As[base + 64]  = l0.v;
        As[base + 128] = h1.v;
        As[base + 192] = l1.v;
    }
    __syncthreads();

    const bf16x8* As = (const bf16x8*)Af;
    const float LOG2E = 1.4426950408889634f;
    const float REPS  = 6.25e-6f;                // ratio*eps

    #pragma unroll 2
    for (int tt = 0; tt < 8; ++tt) {
        const int ab = tt * 256 + lane;
        bf16x8 xh0 = As[ab];
        bf16x8 xl0 = As[ab + 64];
        bf16x8 xh1 = As[ab + 128];
        bf16x8 xl1 = As[ab + 192];
        float4 dl  = *(const float4*)&dlg[tt * 16 + q * 4];

        float* ob = out + (t0 + tt * 16 + q * 4) * 256 + wave * 32 + li;
        #pragma unroll
        for (int nf = 0; nf < 2; ++nf) {
            f32x4 acc = {0.f, 0.f, 0.f, 0.f};
            acc = __builtin_amdgcn_mfma_f32_16x16x32_bf16(xl0, Ph[nf][0], acc, 0, 0, 0);
            acc = __builtin_amdgcn_mfma_f32_16x16x32_bf16(xh0, Pl[nf][0], acc, 0, 0, 0);
            acc = __builtin_amdgcn_mfma_f32_16x16x32_bf16(xh0, Ph[nf][0], acc, 0, 0, 0);
            acc = __builtin_amdgcn_mfma_f32_16x16x32_bf16(xl1, Ph[nf][1], acc, 0, 0, 0);
            acc = __builtin_amdgcn_mfma_f32_16x16x32_bf16(xh1, Pl[nf][1], acc, 0, 0, 0);
            acc = __builtin_amdgcn_mfma_f32_16x16x32_bf16(xh1, Ph[nf][1], acc, 0, 0, 0);
            // C layout: col = li (feat), row = q*4 + r (token-local)
            ob[0 * 256 + nf * 16] = __builtin_amdgcn_exp2f(fmaf(acc[0], LOG2E, dl.x)) + REPS;
            ob[1 * 256 + nf * 16] = __builtin_amdgcn_exp2f(fmaf(acc[1], LOG2E, dl.y)) + REPS;
            ob[2 * 256 + nf * 16] = __builtin_amdgcn_exp2f(fmaf(acc[2], LOG2E, dl.z)) + REPS;
            ob[3 * 256 + nf * 16] = __builtin_amdgcn_exp2f(fmaf(acc[3], LOG2E, dl.w)) + REPS;
        }
    }
}

extern "C" void kernel_launch(void* const* d_in, const int* in_sizes, int n_in,
                              void* d_out, int out_size, void* d_ws, size_t ws_size,
                              hipStream_t stream) {
    const float* x    = (const float*)d_in[0];
    const float* proj = (const float*)d_in[1];
    float* out        = (float*)d_out;
    const int ntok    = in_sizes[0] / 64;        // 131072

    performer_fm_kernel<<<ntok / 128, 512, 0, stream>>>(x, proj, out);
}